// Round 7
// baseline (107.965 us; speedup 1.0000x reference)
//
#include <hip/hip_runtime.h>

// EdgeConsistencyLoss: mean((|∇edit| - |∇src|)^2) with Sobel 3x3, SAME zero pad.
// [B=16, C=8, H=512, W=512] fp32 -> 128 independent 512x512 images.
//
// R1: occupancy alone didn't help; halo bytes hurt. Time ~ HBM bytes.
// R2: sw-pipeline depth-1: 52.5us.
// R3: 64-VGPR cap -> spill (WRITE 174MB) -> 123us. Reverted.
// R4: shfl halos + seam regs + depth-2 prefetch: 50.9us, 64 VGPR, FETCH 138.8MB.
// R5: packed v2f + single-sqrt: 57.0us. VALU busy dropped (25->20us) but stalls
//     grew; scalar-rate math says identity is cost-neutral. REVERTED to R4 math.
// R6: fuse stage2 into stage1 (last-block reduction via threadfence + ticket).
//     Kills the 2nd dispatch + inter-kernel drain (~3-5us). Core = R4 verbatim.

#define EPS 1e-8f

constexpr int W_DIM  = 512;
constexpr int H_DIM  = 512;
constexpr int NIMG   = 128;           // B*C
constexpr int ROWS   = 32;            // rows per block chunk (multiple of 4)
constexpr int CHUNKS = H_DIM / ROWS;  // 16
constexpr int TPB    = 128;           // 2 waves; block covers full 512-px width
constexpr int NBLK   = NIMG * CHUNKS; // 2048
constexpr double TOTAL_ELEMS = 33554432.0; // 16*8*512*512

struct RowBuf { float4 s, e; float ss, es; };

__global__ __launch_bounds__(TPB) void edge_loss_fused(
    const float* __restrict__ src, const float* __restrict__ edt,
    float* __restrict__ partial, unsigned int* __restrict__ ticket,
    float* __restrict__ out)
{
    const int blk  = blockIdx.x;
    const int img  = blk / CHUNKS;
    const int r0   = (blk % CHUNKS) * ROWS;
    const int wv   = threadIdx.x >> 6;
    const int lane = threadIdx.x & 63;
    const int c0   = threadIdx.x * 4;   // wave0: cols 0..255, wave1: 256..511

    const float* simg = src + (size_t)img * (H_DIM * W_DIM);
    const float* eimg = edt + (size_t)img * (H_DIM * W_DIM);

    // Wave-seam: wave0 lane63 needs col 256; wave1 lane0 needs col 255.
    // Image edges (col -1, col 512) are zero-pad; seam reg stays 0 there.
    const bool seam_active = (wv == 0) ? (lane == 63) : (lane == 0);
    const int  seamcol     = (wv == 0) ? 256 : 255;

    // Streaming Sobel state per column i (P: gx partials, Q: b history):
    //   a(h) = x[h,w+1]-x[h,w-1];  b(h) = x[h,w-1]+2x[h,w]+x[h,w+1]
    //   gx(h-1) = P0 + a(h);  gy(h-1) = b(h) - Q0
    //   P0' = P1 + 2a(h); P1' = a(h); Q0' = Q1; Q1' = b(h)
    float sP0[4], sP1[4], sQ0[4], sQ1[4];
    float eP0[4], eP1[4], eQ0[4], eQ1[4];
    float acc = 0.f;

    auto issue = [&](int h, RowBuf& rb) {
        int hc = h < 0 ? 0 : (h >= H_DIM ? H_DIM - 1 : h);
        const float* srow = simg + (size_t)hc * W_DIM;
        const float* erow = eimg + (size_t)hc * W_DIM;
        rb.s = *reinterpret_cast<const float4*>(srow + c0);
        rb.e = *reinterpret_cast<const float4*>(erow + c0);
        rb.ss = 0.f; rb.es = 0.f;
        if (seam_active) { rb.ss = srow[seamcol]; rb.es = erow[seamcol]; }
    };

    // Extend the 4 raw pixels to 6 with halos from lane neighbors / seam regs.
    auto halos = [&](const RowBuf& rb, float sp[6], float ep[6]) {
        float slT = __shfl_up(rb.s.w, 1);
        float srT = __shfl_down(rb.s.x, 1);
        float elT = __shfl_up(rb.e.w, 1);
        float erT = __shfl_down(rb.e.x, 1);
        sp[0] = (lane == 0)  ? rb.ss : slT;   // wave0 lane0: ss==0 (image edge)
        sp[5] = (lane == 63) ? rb.ss : srT;   // wave1 lane63: ss==0
        ep[0] = (lane == 0)  ? rb.es : elT;
        ep[5] = (lane == 63) ? rb.es : erT;
        sp[1]=rb.s.x; sp[2]=rb.s.y; sp[3]=rb.s.z; sp[4]=rb.s.w;
        ep[1]=rb.e.x; ep[2]=rb.e.y; ep[3]=rb.e.z; ep[4]=rb.e.w;
    };

    // Consume raw row h: emit output row h-1, advance state.
    auto consume = [&](const RowBuf& rb, int h) {
        if (h < H_DIM) {                      // wave-uniform branch
            float sp[6], ep[6];
            halos(rb, sp, ep);
            #pragma unroll
            for (int i = 0; i < 4; ++i) {
                float a  = sp[i+2] - sp[i];
                float b  = sp[i] + 2.f*sp[i+1] + sp[i+2];
                float gx = sP0[i] + a;
                float gy = b - sQ0[i];
                sP0[i] = fmaf(2.f, a, sP1[i]); sP1[i] = a;
                sQ0[i] = sQ1[i]; sQ1[i] = b;
                float es = __builtin_amdgcn_sqrtf(fmaf(gx, gx, fmaf(gy, gy, EPS)));
                float a2  = ep[i+2] - ep[i];
                float b2  = ep[i] + 2.f*ep[i+1] + ep[i+2];
                float gx2 = eP0[i] + a2;
                float gy2 = b2 - eQ0[i];
                eP0[i] = fmaf(2.f, a2, eP1[i]); eP1[i] = a2;
                eQ0[i] = eQ1[i]; eQ1[i] = b2;
                float ee = __builtin_amdgcn_sqrtf(fmaf(gx2, gx2, fmaf(gy2, gy2, EPS)));
                float d = ee - es;
                acc = fmaf(d, d, acc);
            }
        } else {                              // zero-pad row below image
            #pragma unroll
            for (int i = 0; i < 4; ++i) {
                float gx = sP0[i], gy = -sQ0[i];
                sP0[i] = sP1[i]; sP1[i] = 0.f; sQ0[i] = sQ1[i]; sQ1[i] = 0.f;
                float es = __builtin_amdgcn_sqrtf(fmaf(gx, gx, fmaf(gy, gy, EPS)));
                float gx2 = eP0[i], gy2 = -eQ0[i];
                eP0[i] = eP1[i]; eP1[i] = 0.f; eQ0[i] = eQ1[i]; eQ1[i] = 0.f;
                float ee = __builtin_amdgcn_sqrtf(fmaf(gx2, gx2, fmaf(gy2, gy2, EPS)));
                float d = ee - es;
                acc = fmaf(d, d, acc);
            }
        }
    };

    // ---- Prologue: 4 rows in flight before first consume. ----
    RowBuf bA0, bA1, bB0, bB1;
    issue(r0 - 1, bA0);
    issue(r0,     bA1);
    issue(r0 + 1, bB0);
    issue(r0 + 2, bB1);

    if (r0 > 0) {          // row r0-1 exists: P0 = a, Q0 = b
        float sp[6], ep[6];
        halos(bA0, sp, ep);
        #pragma unroll
        for (int i = 0; i < 4; ++i) {
            sP0[i] = sp[i+2] - sp[i];
            sQ0[i] = sp[i] + 2.f*sp[i+1] + sp[i+2];
            eP0[i] = ep[i+2] - ep[i];
            eQ0[i] = ep[i] + 2.f*ep[i+1] + ep[i+2];
        }
    } else {
        #pragma unroll
        for (int i = 0; i < 4; ++i) { sP0[i]=0.f; sQ0[i]=0.f; eP0[i]=0.f; eQ0[i]=0.f; }
    }
    {   // row r0: P0 += 2a, P1 = a, Q1 = b
        float sp[6], ep[6];
        halos(bA1, sp, ep);
        #pragma unroll
        for (int i = 0; i < 4; ++i) {
            float a  = sp[i+2] - sp[i];
            sP0[i] = fmaf(2.f, a, sP0[i]); sP1[i] = a;
            sQ1[i] = sp[i] + 2.f*sp[i+1] + sp[i+2];
            float a2 = ep[i+2] - ep[i];
            eP0[i] = fmaf(2.f, a2, eP0[i]); eP1[i] = a2;
            eQ1[i] = ep[i] + 2.f*ep[i+1] + ep[i+2];
        }
    }

    // ---- Main loop: 4 rows per iteration, A/B pair rotation, depth ~2. ----
    int h = r0 + 1;
    #pragma unroll 1
    for (int k = 0; k < ROWS / 4; ++k, h += 4) {
        if (h + 2 <= r0 + ROWS) issue(h + 2, bA0);
        if (h + 3 <= r0 + ROWS) issue(h + 3, bA1);
        consume(bB0, h);
        consume(bB1, h + 1);
        if (h + 4 <= r0 + ROWS) issue(h + 4, bB0);
        if (h + 5 <= r0 + ROWS) issue(h + 5, bB1);
        consume(bA0, h + 2);
        consume(bA1, h + 3);
    }

    // ---- Block reduction: wave shuffle, then LDS across the 2 waves. ----
    #pragma unroll
    for (int off = 32; off > 0; off >>= 1)
        acc += __shfl_down(acc, off);
    __shared__ float wsum[TPB / 64];
    if (lane == 0) wsum[wv] = acc;
    __syncthreads();
    __shared__ bool amlast;
    if (threadIdx.x == 0) {
        float tot = 0.f;
        #pragma unroll
        for (int i = 0; i < TPB / 64; ++i) tot += wsum[i];
        partial[blk] = tot;
        __threadfence();                       // partial visible device-wide
        unsigned int t = atomicAdd(ticket, 1u);// device-scope
        amlast = (t == (unsigned int)(NBLK - 1));
    }
    __syncthreads();

    // ---- Last block re-reduces all partials (fixed order => deterministic).
    if (amlast) {
        __threadfence();                       // acquire side
        float s = 0.f;
        #pragma unroll 4
        for (int i = threadIdx.x; i < NBLK; i += TPB)
            s += partial[i];
        #pragma unroll
        for (int off = 32; off > 0; off >>= 1)
            s += __shfl_down(s, off);
        __shared__ float fsum[TPB / 64];
        if (lane == 0) fsum[wv] = s;
        __syncthreads();
        if (threadIdx.x == 0) {
            float tot = 0.f;
            #pragma unroll
            for (int i = 0; i < TPB / 64; ++i) tot += fsum[i];
            out[0] = (float)((double)tot / TOTAL_ELEMS);
        }
    }
}

extern "C" void kernel_launch(void* const* d_in, const int* in_sizes, int n_in,
                              void* d_out, int out_size, void* d_ws, size_t ws_size,
                              hipStream_t stream) {
    const float* src = (const float*)d_in[0];  // source_latent
    const float* edt = (const float*)d_in[1];  // edited_latent
    // d_in[2]/d_in[3] are the fixed Sobel kernels; baked into the math above
    // (flip-sign ambiguity is irrelevant under the magnitude).
    float* out = (float*)d_out;

    // d_ws layout: [0..255] ticket (uint at 0), [256..] partials (NBLK floats).
    unsigned int* ticket = (unsigned int*)d_ws;
    float* partial = (float*)((char*)d_ws + 256);

    hipMemsetAsync(ticket, 0, sizeof(unsigned int), stream);  // graph-safe async
    edge_loss_fused<<<dim3(NBLK), dim3(TPB), 0, stream>>>(src, edt, partial, ticket, out);
}

// Round 8
// 69.553 us; speedup vs baseline: 1.5523x; 1.5523x over previous
//
#include <hip/hip_runtime.h>

// EdgeConsistencyLoss: mean((|∇edit| - |∇src|)^2) with Sobel 3x3, SAME zero pad.
// [B=16, C=8, H=512, W=512] fp32 -> 128 independent 512x512 images.
//
// R1: occupancy alone didn't help; halo bytes hurt. Time ~ HBM bytes.
// R2: sw-pipeline depth-1: 52.5us.
// R3: 64-VGPR cap -> spill (WRITE 174MB) -> 123us. Reverted.
// R4: shfl halos + seam regs + depth-2 prefetch: 50.9us, 64 VGPR, FETCH 138.8MB.
// R5: packed v2f + single-sqrt: 57.0us (VALU down, stalls up). Reverted.
// R6: last-block fused reduction: 108us! Per-block __threadfence (device-scope
//     L2 writeback) poisoned the memory path. Reverted to 2-kernel.
// R7: prefetch depth 3 -> 7 rows (8 named RowBufs, 4 pairs, 8-row iterations).
//     Depth was ~350cy vs ~900cy HBM latency; now ~820cy. VGPR ~120 still
//     >= 4 waves/SIMD (the grid cap). Spill tripwire: WRITE_SIZE.

#define EPS 1e-8f

constexpr int W_DIM  = 512;
constexpr int H_DIM  = 512;
constexpr int NIMG   = 128;           // B*C
constexpr int ROWS   = 32;            // rows per block chunk (multiple of 8)
constexpr int CHUNKS = H_DIM / ROWS;  // 16
constexpr int TPB    = 128;           // 2 waves; block covers full 512-px width
constexpr int NBLK   = NIMG * CHUNKS; // 2048
constexpr double TOTAL_ELEMS = 33554432.0; // 16*8*512*512

struct RowBuf { float4 s, e; float ss, es; };

__global__ __launch_bounds__(TPB) void edge_loss_stage1(
    const float* __restrict__ src, const float* __restrict__ edt,
    float* __restrict__ partial)
{
    const int blk  = blockIdx.x;
    const int img  = blk / CHUNKS;
    const int r0   = (blk % CHUNKS) * ROWS;
    const int wv   = threadIdx.x >> 6;
    const int lane = threadIdx.x & 63;
    const int c0   = threadIdx.x * 4;   // wave0: cols 0..255, wave1: 256..511

    const float* simg = src + (size_t)img * (H_DIM * W_DIM);
    const float* eimg = edt + (size_t)img * (H_DIM * W_DIM);

    // Wave-seam: wave0 lane63 needs col 256; wave1 lane0 needs col 255.
    // Image edges (col -1, col 512) are zero-pad; seam reg stays 0 there.
    const bool seam_active = (wv == 0) ? (lane == 63) : (lane == 0);
    const int  seamcol     = (wv == 0) ? 256 : 255;

    // Streaming Sobel state per column i (P: gx partials, Q: b history):
    //   a(h) = x[h,w+1]-x[h,w-1];  b(h) = x[h,w-1]+2x[h,w]+x[h,w+1]
    //   gx(h-1) = P0 + a(h);  gy(h-1) = b(h) - Q0
    //   P0' = P1 + 2a(h); P1' = a(h); Q0' = Q1; Q1' = b(h)
    float sP0[4], sP1[4], sQ0[4], sQ1[4];
    float eP0[4], eP1[4], eQ0[4], eQ1[4];
    float acc = 0.f;

    auto issue = [&](int h, RowBuf& rb) {
        int hc = h < 0 ? 0 : (h >= H_DIM ? H_DIM - 1 : h);
        const float* srow = simg + (size_t)hc * W_DIM;
        const float* erow = eimg + (size_t)hc * W_DIM;
        rb.s = *reinterpret_cast<const float4*>(srow + c0);
        rb.e = *reinterpret_cast<const float4*>(erow + c0);
        rb.ss = 0.f; rb.es = 0.f;
        if (seam_active) { rb.ss = srow[seamcol]; rb.es = erow[seamcol]; }
    };

    // Extend the 4 raw pixels to 6 with halos from lane neighbors / seam regs.
    auto halos = [&](const RowBuf& rb, float sp[6], float ep[6]) {
        float slT = __shfl_up(rb.s.w, 1);
        float srT = __shfl_down(rb.s.x, 1);
        float elT = __shfl_up(rb.e.w, 1);
        float erT = __shfl_down(rb.e.x, 1);
        sp[0] = (lane == 0)  ? rb.ss : slT;   // wave0 lane0: ss==0 (image edge)
        sp[5] = (lane == 63) ? rb.ss : srT;   // wave1 lane63: ss==0
        ep[0] = (lane == 0)  ? rb.es : elT;
        ep[5] = (lane == 63) ? rb.es : erT;
        sp[1]=rb.s.x; sp[2]=rb.s.y; sp[3]=rb.s.z; sp[4]=rb.s.w;
        ep[1]=rb.e.x; ep[2]=rb.e.y; ep[3]=rb.e.z; ep[4]=rb.e.w;
    };

    // Consume raw row h: emit output row h-1, advance state.
    auto consume = [&](const RowBuf& rb, int h) {
        if (h < H_DIM) {                      // wave-uniform branch
            float sp[6], ep[6];
            halos(rb, sp, ep);
            #pragma unroll
            for (int i = 0; i < 4; ++i) {
                float a  = sp[i+2] - sp[i];
                float b  = sp[i] + 2.f*sp[i+1] + sp[i+2];
                float gx = sP0[i] + a;
                float gy = b - sQ0[i];
                sP0[i] = fmaf(2.f, a, sP1[i]); sP1[i] = a;
                sQ0[i] = sQ1[i]; sQ1[i] = b;
                float es = __builtin_amdgcn_sqrtf(fmaf(gx, gx, fmaf(gy, gy, EPS)));
                float a2  = ep[i+2] - ep[i];
                float b2  = ep[i] + 2.f*ep[i+1] + ep[i+2];
                float gx2 = eP0[i] + a2;
                float gy2 = b2 - eQ0[i];
                eP0[i] = fmaf(2.f, a2, eP1[i]); eP1[i] = a2;
                eQ0[i] = eQ1[i]; eQ1[i] = b2;
                float ee = __builtin_amdgcn_sqrtf(fmaf(gx2, gx2, fmaf(gy2, gy2, EPS)));
                float d = ee - es;
                acc = fmaf(d, d, acc);
            }
        } else {                              // zero-pad row below image
            #pragma unroll
            for (int i = 0; i < 4; ++i) {
                float gx = sP0[i], gy = -sQ0[i];
                sP0[i] = sP1[i]; sP1[i] = 0.f; sQ0[i] = sQ1[i]; sQ1[i] = 0.f;
                float es = __builtin_amdgcn_sqrtf(fmaf(gx, gx, fmaf(gy, gy, EPS)));
                float gx2 = eP0[i], gy2 = -eQ0[i];
                eP0[i] = eP1[i]; eP1[i] = 0.f; eQ0[i] = eQ1[i]; eQ1[i] = 0.f;
                float ee = __builtin_amdgcn_sqrtf(fmaf(gx2, gx2, fmaf(gy2, gy2, EPS)));
                float d = ee - es;
                acc = fmaf(d, d, acc);
            }
        }
    };

    // ---- Prologue: state-init rows first, then 7 rows in flight. ----
    RowBuf bA0, bA1, bB0, bB1, bC0, bC1, bD0, bD1;
    issue(r0 - 1, bA0);
    issue(r0,     bA1);
    issue(r0 + 1, bB0);
    issue(r0 + 2, bB1);
    issue(r0 + 3, bC0);
    issue(r0 + 4, bC1);
    issue(r0 + 5, bD0);
    issue(r0 + 6, bD1);

    if (r0 > 0) {          // row r0-1 exists: P0 = a, Q0 = b
        float sp[6], ep[6];
        halos(bA0, sp, ep);
        #pragma unroll
        for (int i = 0; i < 4; ++i) {
            sP0[i] = sp[i+2] - sp[i];
            sQ0[i] = sp[i] + 2.f*sp[i+1] + sp[i+2];
            eP0[i] = ep[i+2] - ep[i];
            eQ0[i] = ep[i] + 2.f*ep[i+1] + ep[i+2];
        }
    } else {
        #pragma unroll
        for (int i = 0; i < 4; ++i) { sP0[i]=0.f; sQ0[i]=0.f; eP0[i]=0.f; eQ0[i]=0.f; }
    }
    {   // row r0: P0 += 2a, P1 = a, Q1 = b
        float sp[6], ep[6];
        halos(bA1, sp, ep);
        #pragma unroll
        for (int i = 0; i < 4; ++i) {
            float a  = sp[i+2] - sp[i];
            sP0[i] = fmaf(2.f, a, sP0[i]); sP1[i] = a;
            sQ1[i] = sp[i] + 2.f*sp[i+1] + sp[i+2];
            float a2 = ep[i+2] - ep[i];
            eP0[i] = fmaf(2.f, a2, eP0[i]); eP1[i] = a2;
            eQ1[i] = ep[i] + 2.f*ep[i+1] + ep[i+2];
        }
    }
    issue(r0 + 7, bA0);
    issue(r0 + 8, bA1);
    // In flight now: rows r0+1 .. r0+8 (pairs B,C,D,A).

    // ---- Main loop: 8 rows per iteration, pair rotation B,C,D,A; depth ~7. ----
    int h = r0 + 1;
    #pragma unroll 1
    for (int k = 0; k < ROWS / 8; ++k, h += 8) {
        consume(bB0, h);
        consume(bB1, h + 1);
        if (h + 8 <= r0 + ROWS) issue(h + 8, bB0);
        if (h + 9 <= r0 + ROWS) issue(h + 9, bB1);
        consume(bC0, h + 2);
        consume(bC1, h + 3);
        if (h + 10 <= r0 + ROWS) issue(h + 10, bC0);
        if (h + 11 <= r0 + ROWS) issue(h + 11, bC1);
        consume(bD0, h + 4);
        consume(bD1, h + 5);
        if (h + 12 <= r0 + ROWS) issue(h + 12, bD0);
        if (h + 13 <= r0 + ROWS) issue(h + 13, bD1);
        consume(bA0, h + 6);
        consume(bA1, h + 7);
        if (h + 14 <= r0 + ROWS) issue(h + 14, bA0);
        if (h + 15 <= r0 + ROWS) issue(h + 15, bA1);
    }

    // ---- Reduction: wave shuffle, then LDS across the 2 waves. ----
    #pragma unroll
    for (int off = 32; off > 0; off >>= 1)
        acc += __shfl_down(acc, off);
    __shared__ float wsum[TPB / 64];
    if (lane == 0) wsum[wv] = acc;
    __syncthreads();
    if (threadIdx.x == 0) {
        float tot = 0.f;
        #pragma unroll
        for (int i = 0; i < TPB / 64; ++i) tot += wsum[i];
        partial[blk] = tot;
    }
}

__global__ __launch_bounds__(256) void edge_loss_stage2(
    const float* __restrict__ partial, float* __restrict__ out, int nparts)
{
    double acc = 0.0;
    for (int i = threadIdx.x; i < nparts; i += 256)
        acc += (double)partial[i];
    #pragma unroll
    for (int off = 32; off > 0; off >>= 1)
        acc += __shfl_down(acc, off);
    __shared__ double wsum[4];
    const int wid  = threadIdx.x >> 6;
    const int lane = threadIdx.x & 63;
    if (lane == 0) wsum[wid] = acc;
    __syncthreads();
    if (threadIdx.x == 0) {
        double t = 0.0;
        #pragma unroll
        for (int i = 0; i < 4; ++i) t += wsum[i];
        out[0] = (float)(t / TOTAL_ELEMS);
    }
}

extern "C" void kernel_launch(void* const* d_in, const int* in_sizes, int n_in,
                              void* d_out, int out_size, void* d_ws, size_t ws_size,
                              hipStream_t stream) {
    const float* src = (const float*)d_in[0];  // source_latent
    const float* edt = (const float*)d_in[1];  // edited_latent
    // d_in[2]/d_in[3] are the fixed Sobel kernels; baked into the math above
    // (flip-sign ambiguity is irrelevant under the magnitude).
    float* out     = (float*)d_out;
    float* partial = (float*)d_ws;             // NBLK floats = 8 KB, overwritten every call

    edge_loss_stage1<<<dim3(NBLK), dim3(TPB), 0, stream>>>(src, edt, partial);
    edge_loss_stage2<<<dim3(1), dim3(256), 0, stream>>>(partial, out, NBLK);
}